// Round 5
// baseline (499.270 us; speedup 1.0000x reference)
//
#include <hip/hip_runtime.h>
#include <cstddef>

#define BATCH  4
#define SLEN   2048
#define NHEADS 16
#define DHEAD  64
#define DMODEL 1024

typedef __attribute__((ext_vector_type(8)))  short short8;   // 8 bf16 (4 VGPRs)
typedef __attribute__((ext_vector_type(4)))  float f32x4;    // 16x16 MFMA acc
typedef __attribute__((ext_vector_type(16))) float f32x16;   // 32x32 MFMA acc

// fp32 -> bf16 round-to-nearest-even
__device__ inline unsigned short f2bf(float f) {
    union { float f; unsigned int u; } v; v.f = f;
    unsigned int r = v.u + 0x7fffu + ((v.u >> 16) & 1u);
    return (unsigned short)(r >> 16);
}

__device__ inline float bf2f(unsigned short u) {
    union { unsigned int u; float f; } v; v.u = (unsigned int)u << 16;
    return v.f;
}

__device__ inline float fast_exp2(float x) {
#if __has_builtin(__builtin_amdgcn_exp2f)
    return __builtin_amdgcn_exp2f(x);
#else
    return __expf(x * 0.69314718f);
#endif
}

// async global->LDS, 16 B per lane. LDS dest must be wave-uniform base + lane*16.
__device__ inline void gload_lds16(const unsigned short* g, unsigned short* l) {
    __builtin_amdgcn_global_load_lds(
        (const __attribute__((address_space(1))) void*)g,
        (__attribute__((address_space(3))) void*)l, 16, 0, 0);
}

// ---------------------------------------------------------------------------
// prep: fused x fp32->bf16 convert (blocks 0..4095) + weight transpose+convert
// (blocks 4096..5119).
// ---------------------------------------------------------------------------
__global__ __launch_bounds__(256)
void prep(const float* __restrict__ x, unsigned short* __restrict__ xb,
          const float* __restrict__ W0, const float* __restrict__ W1,
          const float* __restrict__ W2, const float* __restrict__ W3,
          unsigned short* __restrict__ T0, unsigned short* __restrict__ T1,
          unsigned short* __restrict__ T2, unsigned short* __restrict__ T3)
{
    __shared__ unsigned short T[64 * 72];
    const int bid = blockIdx.x;
    const int tid = threadIdx.x;

    if (bid < 4096) {                       // ---- convert part ----
        const int i = bid * 256 + tid;      // n8 = 1048576, exact fit
        const float4 a = ((const float4*)x)[2 * i];
        const float4 b = ((const float4*)x)[2 * i + 1];
        short8 o;
        o[0] = (short)f2bf(a.x); o[1] = (short)f2bf(a.y);
        o[2] = (short)f2bf(a.z); o[3] = (short)f2bf(a.w);
        o[4] = (short)f2bf(b.x); o[5] = (short)f2bf(b.y);
        o[6] = (short)f2bf(b.z); o[7] = (short)f2bf(b.w);
        ((short8*)xb)[i] = o;
        return;
    }

    // ---- wtrans part: W fp32 [K,N] -> Wt bf16 [N,K] ----
    const int idx = bid - 4096;
    const int z = idx >> 8;
    const float* W = (z == 0) ? W0 : (z == 1) ? W1 : (z == 2) ? W2 : W3;
    unsigned short* Wt = (z == 0) ? T0 : (z == 1) ? T1 : (z == 2) ? T2 : T3;
    const int n0 = (idx & 15) * 64, k0 = ((idx >> 4) & 15) * 64;

    #pragma unroll
    for (int it = 0; it < 2; it++) {
        const int t2 = it * 256 + tid;
        const int row = t2 >> 3, col8 = (t2 & 7) * 8;
        const float4 a = *(const float4*)(W + (size_t)(k0 + row) * DMODEL + n0 + col8);
        const float4 b = *(const float4*)(W + (size_t)(k0 + row) * DMODEL + n0 + col8 + 4);
        short8 o;
        o[0] = (short)f2bf(a.x); o[1] = (short)f2bf(a.y);
        o[2] = (short)f2bf(a.z); o[3] = (short)f2bf(a.w);
        o[4] = (short)f2bf(b.x); o[5] = (short)f2bf(b.y);
        o[6] = (short)f2bf(b.z); o[7] = (short)f2bf(b.w);
        *(short8*)&T[row * 72 + col8] = o;
    }
    __syncthreads();
    #pragma unroll
    for (int it = 0; it < 2; it++) {
        const int t2 = it * 256 + tid;
        const int nn = t2 >> 3, k8 = (t2 & 7) * 8;
        short8 v;
        #pragma unroll
        for (int j = 0; j < 8; j++) v[j] = (short)T[(k8 + j) * 72 + nn];
        *(short8*)(Wt + (size_t)(n0 + nn) * DMODEL + k0 + k8) = v;
    }
}

// ---------------------------------------------------------------------------
// bf16 MFMA GEMM, m97 structure. C[M,N] = A[M,K] @ Wt[N,K]^T.
// KIND=0: QKV dispatch — z==0: bf16 row-major Q, PRE-SCALED by 0.125*log2(e);
//         z==1: bf16 K; z==2: bf16 V^T layout [bh][d][s]. KIND=1: fp32 proj.
// ---------------------------------------------------------------------------
template<int KIND>
__global__ __launch_bounds__(256)
void gemm_bf16(const unsigned short* __restrict__ A,
               const unsigned short* __restrict__ B0,
               const unsigned short* __restrict__ B1,
               const unsigned short* __restrict__ B2,
               void* __restrict__ C0v, void* __restrict__ C1v, void* __restrict__ C2v)
{
    constexpr int N = DMODEL, K = DMODEL;
    __shared__ unsigned short As[128 * 64];
    __shared__ unsigned short Bs[128 * 64];

    const int z = blockIdx.z;
    const unsigned short* Bw = (z == 0) ? B0 : (z == 1) ? B1 : B2;
    void* Cv = (z == 0) ? C0v : (z == 1) ? C1v : C2v;

    const int tid  = threadIdx.x;
    const int lane = tid & 63;
    const int wave = tid >> 6;
    const int c  = lane & 15, qd = lane >> 4;
    const int wr = wave >> 1, wc = wave & 1;
    const int m0 = blockIdx.y * 128, n0 = blockIdx.x * 128;

    const unsigned short* ag[4];
    const unsigned short* bg[4];
    unsigned short* al[4];
    unsigned short* bl[4];
    #pragma unroll
    for (int j = 0; j < 4; j++) {
        const int cid = j * 256 + tid;
        const int row = cid >> 3;
        const int k8  = (cid & 7) ^ (row & 7);
        ag[j] = A  + (size_t)(m0 + row) * K + k8 * 8;
        bg[j] = Bw + (size_t)(n0 + row) * K + k8 * 8;
        al[j] = &As[cid * 8];
        bl[j] = &Bs[cid * 8];
    }

    f32x4 acc[4][4];
    #pragma unroll
    for (int mb = 0; mb < 4; mb++)
        #pragma unroll
        for (int nb = 0; nb < 4; nb++)
            #pragma unroll
            for (int r = 0; r < 4; r++) acc[mb][nb][r] = 0.f;

    for (int k0 = 0; k0 < K; k0 += 64) {
        __syncthreads();
        #pragma unroll
        for (int j = 0; j < 4; j++) {
            gload_lds16(ag[j], al[j]);
            gload_lds16(bg[j], bl[j]);
            ag[j] += 64; bg[j] += 64;
        }
        __syncthreads();

        #pragma unroll
        for (int ks = 0; ks < 2; ks++) {
            const int sw = (ks * 4 + qd) ^ (c & 7);
            short8 af[4], bf[4];
            #pragma unroll
            for (int mb = 0; mb < 4; mb++)
                af[mb] = *(const short8*)&As[((wr * 64 + mb * 16 + c) * 8 + sw) * 8];
            #pragma unroll
            for (int nb = 0; nb < 4; nb++)
                bf[nb] = *(const short8*)&Bs[((wc * 64 + nb * 16 + c) * 8 + sw) * 8];
            #pragma unroll
            for (int mb = 0; mb < 4; mb++)
                #pragma unroll
                for (int nb = 0; nb < 4; nb++)
                    acc[mb][nb] = __builtin_amdgcn_mfma_f32_16x16x32_bf16(
                        af[mb], bf[nb], acc[mb][nb], 0, 0, 0);
        }
    }

    const int mbase = m0 + wr * 64 + qd * 4;
    const int nbase = n0 + wc * 64 + c;
    if (KIND == 1) {
        float* C = (float*)Cv;
        #pragma unroll
        for (int mb = 0; mb < 4; mb++)
            #pragma unroll
            for (int nb = 0; nb < 4; nb++)
                #pragma unroll
                for (int r = 0; r < 4; r++)
                    C[(size_t)(mbase + mb * 16 + r) * N + nbase + nb * 16] = acc[mb][nb][r];
    } else if (z != 2) {
        unsigned short* C = (unsigned short*)Cv;
        const float osc = (z == 0) ? 0.18033688f : 1.0f;  // Q: 0.125*log2(e)
        #pragma unroll
        for (int mb = 0; mb < 4; mb++)
            #pragma unroll
            for (int nb = 0; nb < 4; nb++)
                #pragma unroll
                for (int r = 0; r < 4; r++)
                    C[(size_t)(mbase + mb * 16 + r) * N + nbase + nb * 16] =
                        f2bf(acc[mb][nb][r] * osc);
    } else {
        // V^T layout: vtb[(b*16+h)*64+dd][s], r = 4 consecutive s
        unsigned short* C = (unsigned short*)Cv;
        const int b = mbase >> 11;
        #pragma unroll
        for (int mb = 0; mb < 4; mb++) {
            const int s = (mbase + mb * 16) & 2047;
            #pragma unroll
            for (int nb = 0; nb < 4; nb++) {
                const int n = nbase + nb * 16;
                const int h = n >> 6, dd = n & 63;
                ushort4 val = make_ushort4(f2bf(acc[mb][nb][0]), f2bf(acc[mb][nb][1]),
                                           f2bf(acc[mb][nb][2]), f2bf(acc[mb][nb][3]));
                *(ushort4*)(C + ((size_t)((b * 16 + h) * 64 + dd)) * SLEN + s) = val;
            }
        }
    }
}

// ---------------------------------------------------------------------------
// MFMA bf16 flash attention v11 — reuse-2 (64 q/wave: each K/V LDS fragment
// feeds 2 MFMAs, halving LDS reads/MFMA — the round-1/4 lesson that LDS read
// throughput is the limiter) at 3 blocks/CU via __launch_bounds__(256,3)
// (170-reg unified cap) + split-K halves (grid 1024, round-2 structure,
// correctness verified there). Register fit vs round-2's 190-reg spill:
//   - QK per q-block SEQUENTIAL: one sacc (16 regs) instead of two (32)
//   - kf[4] cached per 32-key block (K reads unchanged, reused by both q-blocks)
//   - softmax processed in halves of 8 (p[] liveness halved)
// Expected peak ~160-168 unified regs (acc 64 AGPR + qf 32 + working set).
// Partial outputs: per-half normalized O (bf16) + raw row-sum l (fp32);
// combine pass computes O = (l0*O0 + l1*O1)/(l0+l1).
// ---------------------------------------------------------------------------
__global__ __launch_bounds__(256, 3)
void attn_mfma11(const unsigned short* __restrict__ qb,
                 const unsigned short* __restrict__ kb,
                 const unsigned short* __restrict__ vtb,
                 unsigned short* __restrict__ op0,
                 unsigned short* __restrict__ op1,
                 float* __restrict__ lp0,
                 float* __restrict__ lp1)
{
    __shared__ unsigned short lds[18432];   // 36864 B
    unsigned short* Ks = lds;               // 64 keys x 8 chunks (swizzled, rows permuted)
    unsigned short* Vs = lds + 4096;        // 64 d    x 8 chunks (swizzled)

    const int tid = threadIdx.x;
    const int w   = tid >> 6, ln = tid & 63;
    const int c5  = ln & 31;
    const int l5i = ln >> 5;

    // 1024 blocks; (L&7)*128 + L>>3 bijective; XCD k gets bh in [k*8, k*8+8).
    const int L  = blockIdx.x + (int)gridDim.x * blockIdx.y;
    const int wg = (L & 7) * 128 + (L >> 3);
    const int qt   = wg & 7;
    const int half = (wg >> 3) & 1;
    const int bh   = wg >> 4;
    const int b = bh >> 4, h = bh & 15;
    const size_t bh_base = ((size_t)b * SLEN * NHEADS + h) * 64;
    constexpr int RS = NHEADS * 64;                 // 1024

    unsigned short* Op = half ? op1 : op0;
    float*          Lp = half ? lp1 : lp0;

    // staging: LDS row R = w*8+srow (and +32), chunk ln&7 holds source chunk
    // (ln&7)^srow.  K source row = swap23(R): bits 2<->3 of the 5-bit index.
    const int srow = ln >> 3;
    const int sk8  = (ln & 7) ^ srow;
    const int prow = (srow & 3) | ((w & 1) << 2) | (((srow >> 2) & 1) << 3) | ((w >> 1) << 4);
    const unsigned short* kg0 = kb + bh_base + (size_t)(half * 1024 + prow) * RS + sk8 * 8;
    const unsigned short* kg1 = kg0 + (size_t)32 * RS;
    const unsigned short* vg0 = vtb + ((size_t)bh * 64 + w * 8 + srow) * SLEN
                                    + half * 1024 + sk8 * 8;
    const unsigned short* vg1 = vg0 + (size_t)32 * SLEN;
    unsigned short* kl0 = &Ks[(w * 64 + ln) * 8];
    unsigned short* kl1 = kl0 + 2048;
    unsigned short* vl0 = &Vs[(w * 64 + ln) * 8];
    unsigned short* vl1 = vl0 + 2048;

    const int qtile = qt * 256 + w * 64;

    // Q fragments from global: qf[qb32][kstep], q = qtile + qb32*32 + c5,
    // B-operand k = l5i*8 + j within each 16-slice of d. Pre-scaled.
    short8 qf[2][4];
    #pragma unroll
    for (int qb2 = 0; qb2 < 2; qb2++)
        #pragma unroll
        for (int kst = 0; kst < 4; kst++)
            qf[qb2][kst] = *(const short8*)(qb + bh_base +
                (size_t)(qtile + qb2 * 32 + c5) * RS + kst * 16 + l5i * 8);

    f32x16 acc[2][2];                       // [db32][qb32]
    #pragma unroll
    for (int db = 0; db < 2; db++)
        #pragma unroll
        for (int qb2 = 0; qb2 < 2; qb2++)
            #pragma unroll
            for (int r = 0; r < 16; r++) acc[db][qb2][r] = 0.f;
    float lsum[2] = {0.f, 0.f};
    const int cl7 = c5 & 7;

    for (int kt = 0; kt < 16; kt++) {
        __syncthreads();                    // prev tile's K/V reads done
        gload_lds16(kg0, kl0); gload_lds16(kg1, kl1);
        gload_lds16(vg0, vl0); gload_lds16(vg1, vl1);
        kg0 += (size_t)64 * RS; kg1 += (size_t)64 * RS; vg0 += 64; vg1 += 64;
        __syncthreads();                    // vmcnt drain: LDS populated

        #pragma unroll
        for (int kb32 = 0; kb32 < 2; kb32++) {
            // K fragments once per 32-key block, reused by both q-blocks
            short8 kf[4];
            #pragma unroll
            for (int kst = 0; kst < 4; kst++) {
                const int slot = (kst * 2 + l5i) ^ cl7;
                kf[kst] = *(const short8*)&Ks[((kb32 * 32 + c5) * 8 + slot) * 8];
            }

            // sequential per-q-block: S^T = K.Q^T, then static softmax +
            // truncation-pack (in halves of 8 to shorten p liveness).
            // Lane (l5,c5) reg r holds phys key (r&7)+8*l5+16*(r>>3);
            // pk[4*kk+t] is dword t of the PV B-fragment for 16-key step kk.
            unsigned pk[2][8];
            #pragma unroll
            for (int qb2 = 0; qb2 < 2; qb2++) {
                f32x16 sacc;
                #pragma unroll
                for (int r = 0; r < 16; r++) sacc[r] = 0.f;
                __builtin_amdgcn_s_setprio(1);
                #pragma unroll
                for (int kst = 0; kst < 4; kst++)
                    sacc = __builtin_amdgcn_mfma_f32_32x32x16_bf16(
                        kf[kst], qf[qb2][kst], sacc, 0, 0, 0);
                __builtin_amdgcn_s_setprio(0);

                float lacc = 0.f;
                #pragma unroll
                for (int hh = 0; hh < 2; hh++) {
                    float p[8];
                    float s0 = 0.f, s1 = 0.f;
                    #pragma unroll
                    for (int r = 0; r < 8; r += 2) {
                        p[r]     = fast_exp2(sacc[hh * 8 + r]);
                        p[r + 1] = fast_exp2(sacc[hh * 8 + r + 1]);
                        s0 += p[r]; s1 += p[r + 1];
                    }
                    lacc += s0 + s1;
                    #pragma unroll
                    for (int i = 0; i < 4; i++)
                        pk[qb2][hh * 4 + i] = __builtin_amdgcn_perm(
                            __float_as_uint(p[2 * i + 1]), __float_as_uint(p[2 * i]),
                            0x07060302u);
                }
                lsum[qb2] += lacc;
            }

            // O^T[d][q] += V^T . P^T for the two 16-key steps of this kb32
            #pragma unroll
            for (int kk = 0; kk < 2; kk++) {
                const int k2 = kb32 * 2 + kk;
                short8 pf[2];
                #pragma unroll
                for (int qb2 = 0; qb2 < 2; qb2++) {
                    union { unsigned u[4]; short8 s; } t;
                    t.u[0] = pk[qb2][4 * kk + 0];
                    t.u[1] = pk[qb2][4 * kk + 1];
                    t.u[2] = pk[qb2][4 * kk + 2];
                    t.u[3] = pk[qb2][4 * kk + 3];
                    pf[qb2] = t.s;
                }
                __builtin_amdgcn_s_setprio(1);
                #pragma unroll
                for (int db = 0; db < 2; db++) {
                    const int slot = (k2 * 2 + l5i) ^ cl7;
                    short8 vf = *(const short8*)&Vs[((db * 32 + c5) * 8 + slot) * 8];
                    #pragma unroll
                    for (int qb2 = 0; qb2 < 2; qb2++)
                        acc[db][qb2] = __builtin_amdgcn_mfma_f32_32x32x16_bf16(
                            vf, pf[qb2], acc[db][qb2], 0, 0, 0);
                }
                __builtin_amdgcn_s_setprio(0);
            }
        }
    }

    // epilogue: l reduce across lane^32 halves; store raw l (fp32) + O/l
    // (bf16) partials. regs -> per-wave LDS [q][d] (stride 72) -> coalesced
    // bf16 global store. Truncation compensation applied in combine pass.
    __syncthreads();                        // all waves done with Ks/Vs
    float inv[2];
    #pragma unroll
    for (int qb2 = 0; qb2 < 2; qb2++) {
        float l = lsum[qb2];
        l += __shfl_xor(l, 32);
        inv[qb2] = 1.0f / l;
        if (l5i == 0)
            Lp[(size_t)bh * SLEN + qtile + qb2 * 32 + c5] = l;
    }
    unsigned short* E = lds + w * 4608;     // 64 x 72 bf16 per wave
    #pragma unroll
    for (int db = 0; db < 2; db++)
        #pragma unroll
        for (int qb2 = 0; qb2 < 2; qb2++)
            #pragma unroll
            for (int u = 0; u < 4; u++) {
                const int d0 = db * 32 + 8 * u + 4 * l5i;
                const int q  = qb2 * 32 + c5;
                ushort4 val = make_ushort4(
                    f2bf(acc[db][qb2][4 * u + 0] * inv[qb2]),
                    f2bf(acc[db][qb2][4 * u + 1] * inv[qb2]),
                    f2bf(acc[db][qb2][4 * u + 2] * inv[qb2]),
                    f2bf(acc[db][qb2][4 * u + 3] * inv[qb2]));
                *(ushort4*)&E[q * 72 + d0] = val;
            }
    __builtin_amdgcn_wave_barrier();        // wave-private region, in-order DS
    #pragma unroll
    for (int it = 0; it < 8; it++) {
        const int t2 = it * 64 + ln;
        const int row = t2 >> 3, col8 = (t2 & 7) * 8;
        short8 o = *(const short8*)&E[row * 72 + col8];
        *(short8*)(Op + bh_base + (size_t)(qtile + row) * RS + col8) = o;
    }
}

// ---------------------------------------------------------------------------
// Split-K combine: O = (l0*O0 + l1*O1)/(l0+l1) * 1.001953125 (truncation
// compensation). Layout [b][s][h][d]; n8 = elems/8.
// ---------------------------------------------------------------------------
__global__ __launch_bounds__(256)
void combine_halves(const unsigned short* __restrict__ o0,
                    const unsigned short* __restrict__ o1,
                    const float* __restrict__ l0,
                    const float* __restrict__ l1,
                    unsigned short* __restrict__ out, int n8)
{
    const int i = blockIdx.x * 256 + threadIdx.x;
    if (i >= n8) return;
    const size_t e = (size_t)i * 8;
    const int b = (int)(e >> 21), s = (int)((e >> 10) & 2047), h = (int)((e >> 6) & 15);
    const int lq = (b * 16 + h) * SLEN + s;
    const float a0 = l0[lq], a1 = l1[lq];
    const float w0 = a0 / (a0 + a1) * 1.001953125f;
    const float w1 = 1.001953125f - w0;
    const short8 v0 = *(const short8*)(o0 + e);
    const short8 v1 = *(const short8*)(o1 + e);
    short8 o;
    #pragma unroll
    for (int j = 0; j < 8; j++)
        o[j] = (short)f2bf(w0 * bf2f((unsigned short)v0[j]) +
                           w1 * bf2f((unsigned short)v1[j]));
    *(short8*)(out + e) = o;
}

// ---------------------------------------------------------------------------
extern "C" void kernel_launch(void* const* d_in, const int* in_sizes, int n_in,
                              void* d_out, int out_size, void* d_ws, size_t ws_size,
                              hipStream_t stream)
{
    const float* x  = (const float*)d_in[0];
    const float* Wq = (const float*)d_in[1];
    const float* Wk = (const float*)d_in[2];
    const float* Wv = (const float*)d_in[3];
    const float* Wo = (const float*)d_in[4];
    float* out = (float*)d_out;

    const size_t per = (size_t)BATCH * SLEN * NHEADS * DHEAD;  // 8,388,608 elems
    const size_t wsz = (size_t)DMODEL * DMODEL;
    unsigned short* qb  = (unsigned short*)d_ws;  // bf16 [b][s][h][d]; combine out aliases
    unsigned short* kb  = qb  + per;
    unsigned short* vtb = kb  + per;              // bf16 [bh][d][s] (written by gemm)
    unsigned short* xb  = vtb + per;              // bf16 [M][K]; dead after gemm<0> -> op0
    unsigned short* wtq = xb  + per;              // bf16 [N][K] x4
    unsigned short* wtk = wtq + wsz;
    unsigned short* wtv = wtk + wsz;
    unsigned short* wto = wtv + wsz;
    unsigned short* op0 = xb;                     // alias (xb consumed by gemm<0>)
    unsigned short* op1 = wto + wsz;              // bf16 partial, half 1
    float* lp0 = (float*)(op1 + per);             // row sums, half 0
    float* lp1 = lp0 + (size_t)BATCH * NHEADS * SLEN;
    // ws use: (4*per + 4*wsz)*2 + per*2 + 2*131072*4 = 93,323,264 B

    dim3 blk(256);
    prep<<<dim3(4096 + 1024), blk, 0, stream>>>(x, xb, Wq, Wk, Wv, Wo,
                                                wtq, wtk, wtv, wto);

    gemm_bf16<0><<<dim3(8, 64, 3), blk, 0, stream>>>(xb, wtq, wtk, wtv, qb, kb, vtb);

    attn_mfma11<<<dim3(16, 64), blk, 0, stream>>>(qb, kb, vtb, op0, op1, lp0, lp1);

    combine_halves<<<dim3((int)(per / 2048)), blk, 0, stream>>>(
        op0, op1, lp0, lp1, qb, (int)(per / 8));

    gemm_bf16<1><<<dim3(8, 64, 1), blk, 0, stream>>>(qb, wto, wto, wto, out, out, out);
}

// Round 6
// 262.554 us; speedup vs baseline: 1.9016x; 1.9016x over previous
//
#include <hip/hip_runtime.h>
#include <cstddef>

#define BATCH  4
#define SLEN   2048
#define NHEADS 16
#define DHEAD  64
#define DMODEL 1024

typedef __attribute__((ext_vector_type(8)))  short short8;   // 8 bf16 (4 VGPRs)
typedef __attribute__((ext_vector_type(4)))  float f32x4;    // 16x16 MFMA acc
typedef __attribute__((ext_vector_type(16))) float f32x16;   // 32x32 MFMA acc

// fp32 -> bf16 round-to-nearest-even
__device__ inline unsigned short f2bf(float f) {
    union { float f; unsigned int u; } v; v.f = f;
    unsigned int r = v.u + 0x7fffu + ((v.u >> 16) & 1u);
    return (unsigned short)(r >> 16);
}

__device__ inline float fast_exp2(float x) {
#if __has_builtin(__builtin_amdgcn_exp2f)
    return __builtin_amdgcn_exp2f(x);
#else
    return __expf(x * 0.69314718f);
#endif
}

// async global->LDS, 16 B per lane. LDS dest must be wave-uniform base + lane*16.
__device__ inline void gload_lds16(const unsigned short* g, unsigned short* l) {
    __builtin_amdgcn_global_load_lds(
        (const __attribute__((address_space(1))) void*)g,
        (__attribute__((address_space(3))) void*)l, 16, 0, 0);
}

// ---------------------------------------------------------------------------
// prep: fused x fp32->bf16 convert (blocks 0..4095) + weight transpose+convert
// (blocks 4096..5119).
// ---------------------------------------------------------------------------
__global__ __launch_bounds__(256)
void prep(const float* __restrict__ x, unsigned short* __restrict__ xb,
          const float* __restrict__ W0, const float* __restrict__ W1,
          const float* __restrict__ W2, const float* __restrict__ W3,
          unsigned short* __restrict__ T0, unsigned short* __restrict__ T1,
          unsigned short* __restrict__ T2, unsigned short* __restrict__ T3)
{
    __shared__ unsigned short T[64 * 72];
    const int bid = blockIdx.x;
    const int tid = threadIdx.x;

    if (bid < 4096) {                       // ---- convert part ----
        const int i = bid * 256 + tid;      // n8 = 1048576, exact fit
        const float4 a = ((const float4*)x)[2 * i];
        const float4 b = ((const float4*)x)[2 * i + 1];
        short8 o;
        o[0] = (short)f2bf(a.x); o[1] = (short)f2bf(a.y);
        o[2] = (short)f2bf(a.z); o[3] = (short)f2bf(a.w);
        o[4] = (short)f2bf(b.x); o[5] = (short)f2bf(b.y);
        o[6] = (short)f2bf(b.z); o[7] = (short)f2bf(b.w);
        ((short8*)xb)[i] = o;
        return;
    }

    // ---- wtrans part: W fp32 [K,N] -> Wt bf16 [N,K] ----
    const int idx = bid - 4096;
    const int z = idx >> 8;
    const float* W = (z == 0) ? W0 : (z == 1) ? W1 : (z == 2) ? W2 : W3;
    unsigned short* Wt = (z == 0) ? T0 : (z == 1) ? T1 : (z == 2) ? T2 : T3;
    const int n0 = (idx & 15) * 64, k0 = ((idx >> 4) & 15) * 64;

    #pragma unroll
    for (int it = 0; it < 2; it++) {
        const int t2 = it * 256 + tid;
        const int row = t2 >> 3, col8 = (t2 & 7) * 8;
        const float4 a = *(const float4*)(W + (size_t)(k0 + row) * DMODEL + n0 + col8);
        const float4 b = *(const float4*)(W + (size_t)(k0 + row) * DMODEL + n0 + col8 + 4);
        short8 o;
        o[0] = (short)f2bf(a.x); o[1] = (short)f2bf(a.y);
        o[2] = (short)f2bf(a.z); o[3] = (short)f2bf(a.w);
        o[4] = (short)f2bf(b.x); o[5] = (short)f2bf(b.y);
        o[6] = (short)f2bf(b.z); o[7] = (short)f2bf(b.w);
        *(short8*)&T[row * 72 + col8] = o;
    }
    __syncthreads();
    #pragma unroll
    for (int it = 0; it < 2; it++) {
        const int t2 = it * 256 + tid;
        const int nn = t2 >> 3, k8 = (t2 & 7) * 8;
        short8 v;
        #pragma unroll
        for (int j = 0; j < 8; j++) v[j] = (short)T[(k8 + j) * 72 + nn];
        *(short8*)(Wt + (size_t)(n0 + nn) * DMODEL + k0 + k8) = v;
    }
}

// ---------------------------------------------------------------------------
// bf16 MFMA GEMM, m97 structure. C[M,N] = A[M,K] @ Wt[N,K]^T.
// KIND=0: QKV dispatch — z==0: bf16 row-major Q, PRE-SCALED by 0.125*log2(e);
//         z==1: bf16 K; z==2: bf16 V^T layout [bh][d][s] written via an LDS
//         transpose so the global stores are fully coalesced 256 B rows
//         (round-5 finding: the direct scattered ushort4 stores at 4 KB
//         stride were 16-way scatter + 2x write amplification).
// KIND=1: final projection — fp32 row-major.
// ---------------------------------------------------------------------------
template<int KIND>
__global__ __launch_bounds__(256)
void gemm_bf16(const unsigned short* __restrict__ A,
               const unsigned short* __restrict__ B0,
               const unsigned short* __restrict__ B1,
               const unsigned short* __restrict__ B2,
               void* __restrict__ C0v, void* __restrict__ C1v, void* __restrict__ C2v)
{
    constexpr int N = DMODEL, K = DMODEL;
    // 17408 shorts = 34816 B. Staging: As = lds[0..8191], Bs = lds[8192..16383].
    // z==2 epilogue reuses the whole buffer as T[128][136] (after barrier).
    __shared__ unsigned short lds[17408];
    unsigned short* As = lds;
    unsigned short* Bs = lds + 8192;

    const int z = blockIdx.z;
    const unsigned short* Bw = (z == 0) ? B0 : (z == 1) ? B1 : B2;
    void* Cv = (z == 0) ? C0v : (z == 1) ? C1v : C2v;

    const int tid  = threadIdx.x;
    const int lane = tid & 63;
    const int wave = tid >> 6;
    const int c  = lane & 15, qd = lane >> 4;
    const int wr = wave >> 1, wc = wave & 1;
    const int m0 = blockIdx.y * 128, n0 = blockIdx.x * 128;

    const unsigned short* ag[4];
    const unsigned short* bg[4];
    unsigned short* al[4];
    unsigned short* bl[4];
    #pragma unroll
    for (int j = 0; j < 4; j++) {
        const int cid = j * 256 + tid;
        const int row = cid >> 3;
        const int k8  = (cid & 7) ^ (row & 7);
        ag[j] = A  + (size_t)(m0 + row) * K + k8 * 8;
        bg[j] = Bw + (size_t)(n0 + row) * K + k8 * 8;
        al[j] = &As[cid * 8];
        bl[j] = &Bs[cid * 8];
    }

    f32x4 acc[4][4];
    #pragma unroll
    for (int mb = 0; mb < 4; mb++)
        #pragma unroll
        for (int nb = 0; nb < 4; nb++)
            #pragma unroll
            for (int r = 0; r < 4; r++) acc[mb][nb][r] = 0.f;

    for (int k0 = 0; k0 < K; k0 += 64) {
        __syncthreads();
        #pragma unroll
        for (int j = 0; j < 4; j++) {
            gload_lds16(ag[j], al[j]);
            gload_lds16(bg[j], bl[j]);
            ag[j] += 64; bg[j] += 64;
        }
        __syncthreads();

        #pragma unroll
        for (int ks = 0; ks < 2; ks++) {
            const int sw = (ks * 4 + qd) ^ (c & 7);
            short8 af[4], bf[4];
            #pragma unroll
            for (int mb = 0; mb < 4; mb++)
                af[mb] = *(const short8*)&As[((wr * 64 + mb * 16 + c) * 8 + sw) * 8];
            #pragma unroll
            for (int nb = 0; nb < 4; nb++)
                bf[nb] = *(const short8*)&Bs[((wc * 64 + nb * 16 + c) * 8 + sw) * 8];
            #pragma unroll
            for (int mb = 0; mb < 4; mb++)
                #pragma unroll
                for (int nb = 0; nb < 4; nb++)
                    acc[mb][nb] = __builtin_amdgcn_mfma_f32_16x16x32_bf16(
                        af[mb], bf[nb], acc[mb][nb], 0, 0, 0);
        }
    }

    const int mbase = m0 + wr * 64 + qd * 4;
    const int nbase = n0 + wc * 64 + c;
    if (KIND == 1) {
        float* C = (float*)Cv;
        #pragma unroll
        for (int mb = 0; mb < 4; mb++)
            #pragma unroll
            for (int nb = 0; nb < 4; nb++)
                #pragma unroll
                for (int r = 0; r < 4; r++)
                    C[(size_t)(mbase + mb * 16 + r) * N + nbase + nb * 16] = acc[mb][nb][r];
    } else if (z != 2) {
        unsigned short* C = (unsigned short*)Cv;
        const float osc = (z == 0) ? 0.18033688f : 1.0f;  // Q: 0.125*log2(e)
        #pragma unroll
        for (int mb = 0; mb < 4; mb++)
            #pragma unroll
            for (int nb = 0; nb < 4; nb++)
                #pragma unroll
                for (int r = 0; r < 4; r++)
                    C[(size_t)(mbase + mb * 16 + r) * N + nbase + nb * 16] =
                        f2bf(acc[mb][nb][r] * osc);
    } else {
        // V^T via LDS transpose: stage C-tile as T[n_local][m_local] bf16
        // (stride 136 shorts -> 16B-aligned rows), then coalesced 256 B row
        // writes to vtb[(b*16+h)*64+dd][s].
        __syncthreads();                     // all waves done with As/Bs
        unsigned short* T = lds;             // [128][136]
        #pragma unroll
        for (int mb = 0; mb < 4; mb++) {
            const int sl = wr * 64 + qd * 4 + mb * 16;   // local m 0..127
            #pragma unroll
            for (int nb = 0; nb < 4; nb++) {
                const int dl = wc * 64 + nb * 16 + c;    // local n 0..127
                ushort4 val = make_ushort4(f2bf(acc[mb][nb][0]), f2bf(acc[mb][nb][1]),
                                           f2bf(acc[mb][nb][2]), f2bf(acc[mb][nb][3]));
                *(ushort4*)&T[dl * 136 + sl] = val;
            }
        }
        __syncthreads();
        unsigned short* C = (unsigned short*)Cv;
        const int b  = m0 >> 11;
        const int s0 = m0 & 2047;
        #pragma unroll
        for (int it = 0; it < 8; it++) {
            const int chunk = it * 256 + tid;
            const int row  = chunk >> 4;           // local n 0..127
            const int col8 = (chunk & 15) * 8;     // local m offset
            const int n = n0 + row;
            const int h2 = n >> 6, dd = n & 63;
            short8 v = *(const short8*)&T[row * 136 + col8];
            *(short8*)(C + ((size_t)((b * 16 + h2) * 64 + dd)) * SLEN + s0 + col8) = v;
        }
    }
}

// ---------------------------------------------------------------------------
// MFMA bf16 flash attention v6 (round-1 winner, 80.5 µs): 32 q/wave, 128 q
// per block, 1024 blocks = 4 blocks/CU = 4 waves/SIMD. K/V staged in LDS
// (reuse-1). Q pre-scaled by 0.125*log2(e) in the QKV GEMM. XCD-bijective
// swizzle keeps all 16 q-tiles of one (b,h) on one XCD. K staging row
// permutation swap23: the S^T C-layout ownership makes the PV B-fragment
// fully in-lane (v_perm truncation pack, no cross-lane exchange).
// Rounds 2-5 established: reuse-2 spills above 2 blocks/CU (needs ~190 unified
// regs); V-from-global is an uncoalesced gather; K/V dbuf is neutral. This
// structure is the attn local optimum.
// ---------------------------------------------------------------------------
__global__ __launch_bounds__(256, 4)
void attn_mfma6(const unsigned short* __restrict__ qb,
                const unsigned short* __restrict__ kb,
                const unsigned short* __restrict__ vtb,
                unsigned short* __restrict__ O)
{
    __shared__ unsigned short lds[18432];   // 36864 B
    unsigned short* Ks = lds;               // 64 keys x 8 chunks (swizzled, rows permuted)
    unsigned short* Vs = lds + 4096;        // 64 d    x 8 chunks (swizzled)

    const int tid = threadIdx.x;
    const int w   = tid >> 6, ln = tid & 63;
    const int c5  = ln & 31;
    const int l5i = ln >> 5;

    // 1024 blocks; (L&7)*128 + L>>3 is bijective (1024 % 8 == 0) and gives
    // XCD k the contiguous work range [k*128, k*128+128) = bh in [k*8, k*8+8).
    const int L  = blockIdx.x + (int)gridDim.x * blockIdx.y;
    const int wg = (L & 7) * 128 + (L >> 3);
    const int qt = wg & 15, bh = wg >> 4;
    const int b = bh >> 4, h = bh & 15;
    const size_t bh_base = ((size_t)b * SLEN * NHEADS + h) * 64;
    constexpr int RS = NHEADS * 64;                 // 1024

    // staging: LDS row R = w*8+srow (and +32), chunk ln&7 holds source chunk
    // (ln&7)^srow.  K source row = swap23(R): bits 2<->3 of the 5-bit index.
    const int srow = ln >> 3;
    const int sk8  = (ln & 7) ^ srow;
    const int prow = (srow & 3) | ((w & 1) << 2) | (((srow >> 2) & 1) << 3) | ((w >> 1) << 4);
    const unsigned short* kg0 = kb + bh_base + (size_t)prow * RS + sk8 * 8;
    const unsigned short* kg1 = kg0 + (size_t)32 * RS;
    const unsigned short* vg0 = vtb + ((size_t)bh * 64 + w * 8 + srow) * SLEN + sk8 * 8;
    const unsigned short* vg1 = vg0 + (size_t)32 * SLEN;
    unsigned short* kl0 = &Ks[(w * 64 + ln) * 8];
    unsigned short* kl1 = kl0 + 2048;
    unsigned short* vl0 = &Vs[(w * 64 + ln) * 8];
    unsigned short* vl1 = vl0 + 2048;

    const int qtile = qt * 128 + w * 32;

    // Q fragments from global: q = qtile + c5, B-operand k = l5i*8 + j within
    // each 16-slice of d.
    short8 qf[4];
    #pragma unroll
    for (int kst = 0; kst < 4; kst++)
        qf[kst] = *(const short8*)(qb + bh_base +
            (size_t)(qtile + c5) * RS + kst * 16 + l5i * 8);

    f32x16 acc[2];                          // [db32]
    #pragma unroll
    for (int db = 0; db < 2; db++)
        #pragma unroll
        for (int r = 0; r < 16; r++) acc[db][r] = 0.f;
    float lsum = 0.f;
    const int cl7 = c5 & 7;

    for (int kt = 0; kt < SLEN / 64; kt++) {
        __syncthreads();                    // prev tile's K/V reads done
        gload_lds16(kg0, kl0); gload_lds16(kg1, kl1);
        gload_lds16(vg0, vl0); gload_lds16(vg1, vl1);
        kg0 += (size_t)64 * RS; kg1 += (size_t)64 * RS; vg0 += 64; vg1 += 64;
        __syncthreads();                    // vmcnt drain: LDS populated

        #pragma unroll
        for (int kb32 = 0; kb32 < 2; kb32++) {
            // S^T[key][q] = K . Q^T   (32 permuted keys x 32 q, d=64)
            f32x16 sacc;
            #pragma unroll
            for (int r = 0; r < 16; r++) sacc[r] = 0.f;
            __builtin_amdgcn_s_setprio(1);
            #pragma unroll
            for (int kst = 0; kst < 4; kst++) {
                const int slot = (kst * 2 + l5i) ^ cl7;
                short8 kf = *(const short8*)&Ks[((kb32 * 32 + c5) * 8 + slot) * 8];
                sacc = __builtin_amdgcn_mfma_f32_32x32x16_bf16(
                    kf, qf[kst], sacc, 0, 0, 0);
            }
            __builtin_amdgcn_s_setprio(0);

            // static softmax + truncation-pack. Lane (l5,c5) reg r holds
            // phys key (reg&7) + 8*l5 + 16*(reg>>3) -> pk[4*kk+t] is dword t
            // of the B-fragment for 16-key step kk. All in-lane.
            // Q pre-scaled: exponent is already score*0.125*log2(e).
            unsigned pk[8];
            {
                float p[16];
                float s0 = 0.f, s1 = 0.f;
                #pragma unroll
                for (int r = 0; r < 16; r += 2) {
                    p[r]     = fast_exp2(sacc[r]);
                    p[r + 1] = fast_exp2(sacc[r + 1]);
                    s0 += p[r]; s1 += p[r + 1];
                }
                lsum += s0 + s1;
                #pragma unroll
                for (int i = 0; i < 8; i++)
                    pk[i] = __builtin_amdgcn_perm(
                        __float_as_uint(p[2 * i + 1]), __float_as_uint(p[2 * i]),
                        0x07060302u);
            }

            // O^T[d][q] += V^T . P^T for the two 16-key steps of this kb32
            #pragma unroll
            for (int kk = 0; kk < 2; kk++) {
                const int k2 = kb32 * 2 + kk;
                union { unsigned u[4]; short8 s; } t;
                t.u[0] = pk[4 * kk + 0];
                t.u[1] = pk[4 * kk + 1];
                t.u[2] = pk[4 * kk + 2];
                t.u[3] = pk[4 * kk + 3];
                const short8 pf = t.s;
                __builtin_amdgcn_s_setprio(1);
                #pragma unroll
                for (int db = 0; db < 2; db++) {
                    const int slot = (k2 * 2 + l5i) ^ cl7;
                    short8 vf = *(const short8*)&Vs[((db * 32 + c5) * 8 + slot) * 8];
                    acc[db] = __builtin_amdgcn_mfma_f32_32x32x16_bf16(
                        vf, pf, acc[db], 0, 0, 0);
                }
                __builtin_amdgcn_s_setprio(0);
            }
        }
    }

    // epilogue: l reduce across lane^32 halves, regs -> per-wave LDS [q][d]
    // (stride 72) -> coalesced bf16 global store (O aliases qb; own rows only).
    __syncthreads();                        // all waves done with Ks/Vs
    float l = lsum;
    l += __shfl_xor(l, 32);
    const float inv = 1.001953125f / l;     // (1+2^-9) truncation compensation
    unsigned short* E = lds + w * 2304;     // 32 x 72 bf16 per wave
    #pragma unroll
    for (int db = 0; db < 2; db++)
        #pragma unroll
        for (int u = 0; u < 4; u++) {
            const int d0 = db * 32 + 8 * u + 4 * l5i;
            const int q  = c5;
            ushort4 val = make_ushort4(
                f2bf(acc[db][4 * u + 0] * inv),
                f2bf(acc[db][4 * u + 1] * inv),
                f2bf(acc[db][4 * u + 2] * inv),
                f2bf(acc[db][4 * u + 3] * inv));
            *(ushort4*)&E[q * 72 + d0] = val;
        }
    __builtin_amdgcn_wave_barrier();        // wave-private region, in-order DS
    #pragma unroll
    for (int it = 0; it < 4; it++) {
        const int t2 = it * 64 + ln;
        const int row = t2 >> 3, col8 = (t2 & 7) * 8;
        short8 o = *(const short8*)&E[row * 72 + col8];
        *(short8*)(O + bh_base + (size_t)(qtile + row) * RS + col8) = o;
    }
}

// ---------------------------------------------------------------------------
extern "C" void kernel_launch(void* const* d_in, const int* in_sizes, int n_in,
                              void* d_out, int out_size, void* d_ws, size_t ws_size,
                              hipStream_t stream)
{
    const float* x  = (const float*)d_in[0];
    const float* Wq = (const float*)d_in[1];
    const float* Wk = (const float*)d_in[2];
    const float* Wv = (const float*)d_in[3];
    const float* Wo = (const float*)d_in[4];
    float* out = (float*)d_out;

    const size_t per = (size_t)BATCH * SLEN * NHEADS * DHEAD;  // 8,388,608 elems
    const size_t wsz = (size_t)DMODEL * DMODEL;
    unsigned short* qb  = (unsigned short*)d_ws;  // bf16 [b][s][h][d]; attn out aliases
    unsigned short* kb  = qb  + per;
    unsigned short* vtb = kb  + per;              // bf16 [bh][d][s] (written by gemm)
    unsigned short* xb  = vtb + per;              // bf16 [M][K]
    unsigned short* wtq = xb  + per;              // bf16 [N][K] x4
    unsigned short* wtk = wtq + wsz;
    unsigned short* wtv = wtk + wsz;
    unsigned short* wto = wtv + wsz;
    // ws use: (4*per + 4*wsz)*2 = 75,497,472 B

    dim3 blk(256);
    prep<<<dim3(4096 + 1024), blk, 0, stream>>>(x, xb, Wq, Wk, Wv, Wo,
                                                wtq, wtk, wtv, wto);

    gemm_bf16<0><<<dim3(8, 64, 3), blk, 0, stream>>>(xb, wtq, wtk, wtv, qb, kb, vtb);

    attn_mfma6<<<dim3(SLEN / 128, BATCH * NHEADS), blk, 0, stream>>>(qb, kb, vtb, qb);

    gemm_bf16<1><<<dim3(8, 64, 1), blk, 0, stream>>>(qb, wto, wto, wto, out, out, out);
}